// Round 6
// baseline (3961.608 us; speedup 1.0000x reference)
//
#include <hip/hip_runtime.h>
#include <cstdint>
#include <cstddef>

typedef unsigned short u16;
typedef unsigned int   u32;
typedef __attribute__((ext_vector_type(8))) short short8;   // 8 bf16 = 4 VGPRs
typedef __attribute__((ext_vector_type(4))) float f32x4;

// ---------------- bf16 helpers (bit-level) ----------------------------------
__device__ __forceinline__ float bf2f(u16 b) {
  union { u32 u; float f; } v; v.u = ((u32)b) << 16; return v.f;
}
__device__ __forceinline__ u16 f2bf(float f) {
  union { float f; u32 u; } v; v.f = f;
  u32 u = v.u;
  return (u16)((u + 0x7fffu + ((u >> 16) & 1u)) >> 16);  // RNE
}
__device__ __forceinline__ u32 pk2(u16 a, u16 b) { return (u32)a | ((u32)b << 16); }

// ---------------- dtype probe: bf16 vs f32 ----------------------------------
__global__ void detect_dtype(const u16* __restrict__ xin, int* __restrict__ flag) {
  int hits = 0;
  for (int i = threadIdx.x; i < 16384; i += 256) {
    u16 v = xin[i];
    if (((v >> 7) & 0xFF) == 0xFF) hits++;
  }
  if (hits) atomicOr(flag, 1);
}

// ---------------- canonicalize a tensor to bf16 -----------------------------
__global__ __launch_bounds__(256) void convert_bf16(const void* __restrict__ src,
    u16* __restrict__ dst, int n, const int* __restrict__ flag) {
  int i = blockIdx.x * 256 + threadIdx.x;
  if (i >= n) return;
  if (*flag) dst[i] = f2bf(((const float*)src)[i]);
  else       dst[i] = ((const u16*)src)[i];
}

// ---------------- init: x_ws = f32(x_in[:, :64]), input row stride 65 -------
__global__ __launch_bounds__(256) void init_x(const void* __restrict__ xin,
    float* __restrict__ x, const int* __restrict__ flag, int N) {
  int idx = blockIdx.x * 256 + threadIdx.x;
  if (idx >= N * 64) return;
  int n = idx >> 6, c = idx & 63;
  size_t si = (size_t)n * 65 + c;
  float v = (*flag) ? ((const float*)xin)[si] : bf2f(((const u16*)xin)[si]);
  if (!isfinite(v)) v = 0.0f;
  x[idx] = v;
}

// ---------------- per-column sum & sumsq over N rows (initial stats) --------
__global__ __launch_bounds__(256) void col_stats(const float* __restrict__ x,
                                                 float* __restrict__ stats, int N) {
  int c   = threadIdx.x & 63;
  int sub = threadIdx.x >> 6;
  int rows = N / gridDim.x;
  int r0 = blockIdx.x * rows;
  float s = 0.f, s2 = 0.f;
  for (int r = sub; r < rows; r += 4) {
    float v = x[(size_t)(r0 + r) * 64 + c];
    s += v; s2 = fmaf(v, v, s2);
  }
  __shared__ float ls[256], lq[256];
  ls[threadIdx.x] = s; lq[threadIdx.x] = s2;
  __syncthreads();
  if (threadIdx.x < 64) {
    s  = ls[c] + ls[c + 64] + ls[c + 128] + ls[c + 192];
    s2 = lq[c] + lq[c + 64] + lq[c + 128] + lq[c + 192];
    atomicAdd(&stats[c], s);
    atomicAdd(&stats[64 + c], s2);
  }
}

// ============================================================================
// Fused coupling layer, round 6: 512-thread blocks (8 waves), 64 rows/block.
// K-split h0 (two 256-col halves in 32 KB LDS), wave w owns 32-col GEMM1
// output strip -> c1 = 32 regs survives the kh loop. h1 round-trip regions
// live inside h0s (barrier-protected); x1 staging lives inside sred.
// GEMM2 un-padded K=32 chunks; per-path partials merged via LDS f32 atomics.
// LDS = 50,176 B; __launch_bounds__(512,4) -> 2 blocks/CU = 4 waves/SIMD.
// MFMA mapping (validated r3-r5): frags X[r=lane&15][k=(lane>>4)*8+j],
// mfma(A,B) -> D[Arow=q*4+i][Brow=m].
// ============================================================================
__global__ __launch_bounds__(512, 4) void fused_layer(
    float* __restrict__ x, float* __restrict__ det,
    const float* __restrict__ statsC, float* __restrict__ statsN,
    const u16* __restrict__ W0s, const u16* __restrict__ B0s,
    const u16* __restrict__ W1s, const u16* __restrict__ B1s,
    const u16* __restrict__ W2s, const u16* __restrict__ B2s,
    const u16* __restrict__ W0t, const u16* __restrict__ B0t,
    const u16* __restrict__ W1t, const u16* __restrict__ B1t,
    const u16* __restrict__ W2t, const u16* __restrict__ B2t,
    int off1, int first, int N)
{
  __shared__ __align__(16) u16  h0s[64 * 256];      // 32768 B (+ h1w regions)
  __shared__ __align__(16) float sred[2][64][32];   // 16384 B (first 5 KB = x1s)
  __shared__ float musr[128];                       //   512 B
  __shared__ float csum[64], csqs[64];              //   512 B  => 50176 B

  const int tid  = threadIdx.x;
  const int lane = tid & 63, wave = tid >> 6;       // wave 0..7
  const int m = lane & 15, q = lane >> 4;
  const int mb = m & 7;
  const int r0 = blockIdx.x * 64;
  const int off2 = 32 - off1;
  const float invN = 1.0f / (float)N;

  if (tid < 64) {
    float mu  = statsC[tid] * invN;
    float var = fmaxf(statsC[64 + tid] * invN - mu * mu, 0.0f);
    musr[tid]      = mu;
    musr[64 + tid] = 1.0f / sqrtf(var + 1e-5f);
    csum[tid] = 0.0f; csqs[tid] = 0.0f;
  }
  __syncthreads();

  // ---- stage normalized x1 (bf16, stride 40) into sred region ----
  u16* x1s = (u16*)&sred[0][0][0];
  {
    int row = tid >> 3, c4 = (tid & 7) * 4;
    float4 v = *(const float4*)(x + (size_t)(r0 + row) * 64 + off1 + c4);
    float vv[4] = {v.x, v.y, v.z, v.w};
    u16 pk[4];
    #pragma unroll
    for (int u_ = 0; u_ < 4; ++u_) {
      int c = off1 + c4 + u_;
      pk[u_] = f2bf((vv[u_] - musr[c]) * musr[64 + c]);
    }
    *(uint2*)&x1s[row * 40 + c4] = make_uint2(pk2(pk[0], pk[1]), pk2(pk[2], pk[3]));
  }
  __syncthreads();

  short8 xb[4];
  #pragma unroll
  for (int fm = 0; fm < 4; ++fm)
    xb[fm] = *(const short8*)&x1s[(fm * 16 + m) * 40 + q * 8];
  // xb consumed; x1s bytes reclaimed by sred zeroing 2 barriers later.

  u16* h1w = h0s + wave * 2048;     // wave-private 4096 B region inside h0s

  const u16* W0p[2] = {W0s, W0t}; const u16* B0p[2] = {B0s, B0t};
  const u16* W1p[2] = {W1s, W1t}; const u16* B1p[2] = {B1s, B1t};
  const u16* W2p[2] = {W2s, W2t};
  const f32x4 fz = {0.f, 0.f, 0.f, 0.f};

  for (int p = 0; p < 2; ++p) {
    const u16 *W0 = W0p[p], *B0 = B0p[p], *W1 = W1p[p], *B1 = B1p[p], *W2 = W2p[p];

    for (int oc2 = 0; oc2 < 2; ++oc2) {
      const int ocb = oc2 * 256 + wave * 32;    // wave's GEMM1 output strip base
      f32x4 c1[2][4];
      #pragma unroll
      for (int fo = 0; fo < 2; ++fo)
        #pragma unroll
        for (int fm = 0; fm < 4; ++fm) c1[fo][fm] = fz;

      #pragma unroll
      for (int kh = 0; kh < 2; ++kh) {
        __syncthreads();   // protect h0s from previous readers (GEMM1/h1w)
        // ---- GEMM0 half kh: wave computes h0 cols [kh*256+wave*32, +32) ----
        #pragma unroll
        for (int fo = 0; fo < 2; ++fo) {
          int colg = kh * 256 + wave * 32 + fo * 16;
          short8 wa = *(const short8*)(W0 + (size_t)(colg + m) * 32 + q * 8);
          int cb = wave * 32 + fo * 16 + q * 4;      // local col in half
          int gw = cb >> 3, wo = cb & 7;
          float bb[4];
          #pragma unroll
          for (int i2 = 0; i2 < 4; ++i2) bb[i2] = bf2f(B0[colg + q * 4 + i2]);
          #pragma unroll
          for (int fm = 0; fm < 4; ++fm) {
            f32x4 d = __builtin_amdgcn_mfma_f32_16x16x32_bf16(wa, xb[fm], fz, 0, 0, 0);
            u16 pk[4];
            #pragma unroll
            for (int i2 = 0; i2 < 4; ++i2)
              pk[i2] = f2bf(fmaxf(d[i2] + bb[i2], 0.0f));
            int row = fm * 16 + m;
            *(uint2*)&h0s[row * 256 + (((gw ^ (row & 7))) << 3) + wo] =
                make_uint2(pk2(pk[0], pk[1]), pk2(pk[2], pk[3]));
          }
        }
        __syncthreads();
        if (p == 0 && oc2 == 0 && kh == 0) {
          // zero sred (x1s consumed by all waves; first atomicAdd is far away)
          float* sp = &sred[0][0][0];
          #pragma unroll
          for (int i = 0; i < 8; ++i) sp[tid + i * 512] = 0.0f;
        }
        // ---- GEMM1 quarter: K = [kh*256, +256) for output strip ocb ----
        #pragma unroll 2
        for (int ks = 0; ks < 8; ++ks) {
          short8 bf[4];
          #pragma unroll
          for (int fm = 0; fm < 4; ++fm)
            bf[fm] = *(const short8*)&h0s[(fm * 16 + m) * 256 +
                                          ((((ks << 2) | q) ^ mb) << 3)];
          #pragma unroll
          for (int fo = 0; fo < 2; ++fo) {
            short8 wa = *(const short8*)(W1 + (size_t)(ocb + fo * 16 + m) * 512 +
                                         kh * 256 + (ks << 5) + q * 8);
            #pragma unroll
            for (int fm = 0; fm < 4; ++fm)
              c1[fo][fm] = __builtin_amdgcn_mfma_f32_16x16x32_bf16(
                  wa, bf[fm], c1[fo][fm], 0, 0, 0);
          }
        }
      }
      __syncthreads();   // all h0s reads done -> h1w writes into h0s region OK

      // ---- h1 epilogue (relu+b1) -> wave-private h1w ----
      #pragma unroll
      for (int fo = 0; fo < 2; ++fo) {
        float bb[4];
        #pragma unroll
        for (int i2 = 0; i2 < 4; ++i2)
          bb[i2] = bf2f(B1[ocb + fo * 16 + q * 4 + i2]);
        #pragma unroll
        for (int fm = 0; fm < 4; ++fm) {
          u16 pk[4];
          #pragma unroll
          for (int i2 = 0; i2 < 4; ++i2)
            pk[i2] = f2bf(fmaxf(c1[fo][fm][i2] + bb[i2], 0.0f));
          *(uint2*)&h1w[(fm * 16 + m) * 32 + fo * 16 + q * 4] =
              make_uint2(pk2(pk[0], pk[1]), pk2(pk[2], pk[3]));
        }
      }
      asm volatile("s_waitcnt lgkmcnt(0)" ::: "memory");   // same-wave RAW

      // ---- GEMM2 chunk: K = wave's 32 h1 cols (un-padded) ----
      f32x4 a2[4][2];
      #pragma unroll
      for (int fr = 0; fr < 4; ++fr) {
        short8 af = *(const short8*)&h1w[(fr * 16 + m) * 32 + q * 8];
        #pragma unroll
        for (int fo2 = 0; fo2 < 2; ++fo2) {
          short8 wf = *(const short8*)(W2 + (size_t)(fo2 * 16 + m) * 512 +
                                       ocb + q * 8);
          a2[fr][fo2] = __builtin_amdgcn_mfma_f32_16x16x32_bf16(af, wf, fz, 0, 0, 0);
        }
      }
      // merge partial into sred[p] via LDS float atomics
      #pragma unroll
      for (int fr = 0; fr < 4; ++fr)
        #pragma unroll
        for (int fo2 = 0; fo2 < 2; ++fo2)
          #pragma unroll
          for (int i2 = 0; i2 < 4; ++i2)
            atomicAdd(&sred[p][fr * 16 + q * 4 + i2][fo2 * 16 + m],
                      a2[fr][fo2][i2]);
    }
  }
  __syncthreads();   // all atomics visible

  // ---- coupling + det + next-layer stats ----
  {
    int col = tid & 31;
    int rh  = tid >> 5;                  // 0..15
    float muA = musr[off1 + col], rsA = musr[64 + off1 + col];
    float muB = musr[off2 + col], rsB = musr[64 + off2 + col];
    float b2s = bf2f(B2s[col]), b2t = bf2f(B2t[col]);
    float cs1 = 0.f, cq1 = 0.f, cs2 = 0.f, cq2 = 0.f;
    #pragma unroll
    for (int u_ = 0; u_ < 4; ++u_) {
      int row = u_ * 16 + rh;
      float sv = sred[0][row][col] + b2s;
      float tv = sred[1][row][col] + b2t;
      size_t rb = (size_t)(r0 + row) * 64;
      float x1n = (x[rb + off1 + col] - muA) * rsA;
      float x2n = (x[rb + off2 + col] - muB) * rsB;
      float y2 = fmaf(x2n, expf(fminf(sv, 30.0f)), tv);
      x[rb + col]      = x1n;
      x[rb + 32 + col] = y2;
      cs1 += x1n; cq1 = fmaf(x1n, x1n, cq1);
      cs2 += y2;  cq2 = fmaf(y2, y2, cq2);
      float rs_ = sv;
      rs_ += __shfl_xor(rs_, 1);  rs_ += __shfl_xor(rs_, 2);
      rs_ += __shfl_xor(rs_, 4);  rs_ += __shfl_xor(rs_, 8);
      rs_ += __shfl_xor(rs_, 16);
      if (col == 0) {
        int r = r0 + row;
        if (first) det[r] = rs_; else det[r] += rs_;
      }
    }
    cs1 += __shfl_xor(cs1, 32); cq1 += __shfl_xor(cq1, 32);
    cs2 += __shfl_xor(cs2, 32); cq2 += __shfl_xor(cq2, 32);
    if (lane < 32) {
      atomicAdd(&csum[col], cs1);      atomicAdd(&csqs[col], cq1);
      atomicAdd(&csum[32 + col], cs2); atomicAdd(&csqs[32 + col], cq2);
    }
  }
  __syncthreads();
  if (tid < 64) {
    atomicAdd(&statsN[tid],      csum[tid]);
    atomicAdd(&statsN[64 + tid], csqs[tid]);
  }
}

// ---------------- GMM log-likelihood + output writes + partial sums ---------
__global__ __launch_bounds__(256) void gmm_out(const float* __restrict__ x,
    const float* __restrict__ det, const u16* __restrict__ means,
    void* __restrict__ outv, double* __restrict__ acc,
    const int* __restrict__ flag, int N) {
  __shared__ float ms[640];
  __shared__ double rll[256], rdt[256];
  for (int i = threadIdx.x; i < 640; i += 256) ms[i] = bf2f(means[i]);
  __syncthreads();
  int of32 = *flag;
  int n = blockIdx.x * 256 + threadIdx.x;
  double llv = 0.0, dtv = 0.0;
  if (n < N) {
    float y[64];
    size_t rb = (size_t)n * 64;
    #pragma unroll
    for (int c = 0; c < 64; ++c) y[c] = x[rb + c];
    if (of32) {
      float* out = (float*)outv;
      #pragma unroll
      for (int c = 0; c < 64; ++c) out[rb + c] = y[c];
    } else {
      u16* out = (u16*)outv;
      #pragma unroll
      for (int c = 0; c < 64; ++c) out[rb + c] = f2bf(y[c]);
    }
    float lp[10];
    float mx = -3.0e38f;
    #pragma unroll
    for (int k = 0; k < 10; ++k) {
      float d2 = 0.0f;
      #pragma unroll
      for (int c = 0; c < 64; ++c) { float d = y[c] - ms[k * 64 + c]; d2 = fmaf(d, d, d2); }
      float v = -0.5f * (d2 + 64.0f * 1.8378770664093455f) - 2.302585092994046f;
      lp[k] = v; mx = fmaxf(mx, v);
    }
    float se = 0.0f;
    #pragma unroll
    for (int k = 0; k < 10; ++k) se += expf(lp[k] - mx);
    float ll = mx + logf(se);
    float dv = det[n];
    size_t NY = (size_t)N * 64;
    if (of32) {
      float* out = (float*)outv;
      out[NY + 1 + n]     = ll;
      out[NY + 1 + N + n] = dv;
    } else {
      u16* out = (u16*)outv;
      out[NY + 1 + n]     = f2bf(ll);
      out[NY + 1 + N + n] = f2bf(dv);
    }
    llv = ll; dtv = dv;
  }
  rll[threadIdx.x] = llv; rdt[threadIdx.x] = dtv;
  __syncthreads();
  for (int st = 128; st > 0; st >>= 1) {
    if (threadIdx.x < st) {
      rll[threadIdx.x] += rll[threadIdx.x + st];
      rdt[threadIdx.x] += rdt[threadIdx.x + st];
    }
    __syncthreads();
  }
  if (threadIdx.x == 0) { atomicAdd(&acc[0], rll[0]); atomicAdd(&acc[1], rdt[0]); }
}

// ---------------- scalars: loss, ll.mean, det.mean --------------------------
__global__ void finalize(const double* __restrict__ acc, void* __restrict__ outv,
                         const int* __restrict__ flag, int N) {
  double llm = acc[0] / (double)N;
  double dm  = acc[1] / (double)N;
  size_t NY = (size_t)N * 64;
  if (*flag) {
    float* out = (float*)outv;
    out[NY]                         = (float)(-(llm + dm));
    out[NY + 1 + 2 * (size_t)N]     = (float)llm;
    out[NY + 1 + 2 * (size_t)N + 1] = (float)dm;
  } else {
    u16* out = (u16*)outv;
    out[NY]                         = f2bf((float)(-(llm + dm)));
    out[NY + 1 + 2 * (size_t)N]     = f2bf((float)llm);
    out[NY + 1 + 2 * (size_t)N + 1] = f2bf((float)dm);
  }
}

// ============================================================================
extern "C" void kernel_launch(void* const* d_in, const int* in_sizes, int n_in,
                              void* d_out, int out_size, void* d_ws, size_t ws_size,
                              hipStream_t stream) {
  const int N = in_sizes[0] / 65;              // 65536
  (void)n_in; (void)out_size; (void)ws_size;

  char* ws = (char*)d_ws;
  size_t off = 0;
  auto alloc = [&](size_t bytes) -> void* {
    void* p = ws + off; off = (off + bytes + 255) & ~(size_t)255; return p;
  };
  int*    flag  = (int*)   alloc(4);
  double* acc   = (double*)alloc(2 * 8);
  float*  stats = (float*) alloc(9 * 128 * 4);   // slot l = stats of x before layer l
  float*  det   = (float*) alloc((size_t)N * 4);
  float*  x     = (float*) alloc((size_t)N * 64 * 4);

  static const int wcnt[13] = {
    8*512*32, 8*512, 8*512*512, 8*512, 8*32*512, 8*32,   // s-path
    8*512*32, 8*512, 8*512*512, 8*512, 8*32*512, 8*32,   // t-path
    10*64                                                // means
  };
  u16* wptr[13];
  for (int t = 0; t < 13; ++t) wptr[t] = (u16*)alloc((size_t)wcnt[t] * 2);

  // ---- dtype probe + canonicalize ----
  hipMemsetAsync(flag, 0, 4, stream);
  hipMemsetAsync(stats, 0, 9 * 128 * sizeof(float), stream);
  hipMemsetAsync(acc, 0, 2 * sizeof(double), stream);
  detect_dtype<<<dim3(1), dim3(256), 0, stream>>>((const u16*)d_in[0], flag);
  for (int t = 0; t < 13; ++t) {
    int n = wcnt[t];
    convert_bf16<<<dim3((n + 255) / 256), dim3(256), 0, stream>>>(
        d_in[t + 1], wptr[t], n, flag);
  }

  const int NE = N * 64;
  init_x<<<dim3((NE + 255) / 256), dim3(256), 0, stream>>>(d_in[0], x, flag, N);
  col_stats<<<dim3(256), dim3(256), 0, stream>>>(x, stats, N);   // slot 0

  for (int i = 0; i < 8; ++i) {
    fused_layer<<<dim3(N / 64), dim3(512), 0, stream>>>(
        x, det, stats + (size_t)i * 128, stats + (size_t)(i + 1) * 128,
        wptr[0]  + (size_t)i * 512 * 32,  wptr[1]  + (size_t)i * 512,
        wptr[2]  + (size_t)i * 512 * 512, wptr[3]  + (size_t)i * 512,
        wptr[4]  + (size_t)i * 32 * 512,  wptr[5]  + (size_t)i * 32,
        wptr[6]  + (size_t)i * 512 * 32,  wptr[7]  + (size_t)i * 512,
        wptr[8]  + (size_t)i * 512 * 512, wptr[9]  + (size_t)i * 512,
        wptr[10] + (size_t)i * 32 * 512,  wptr[11] + (size_t)i * 32,
        (i & 1) ? 32 : 0, (i == 0) ? 1 : 0, N);
  }

  gmm_out<<<dim3((N + 255) / 256), dim3(256), 0, stream>>>(x, det, wptr[12],
                                                           d_out, acc, flag, N);
  finalize<<<dim3(1), dim3(1), 0, stream>>>(acc, d_out, flag, N);
}

// Round 7
// 1551.902 us; speedup vs baseline: 2.5527x; 2.5527x over previous
//
#include <hip/hip_runtime.h>
#include <cstdint>
#include <cstddef>

typedef unsigned short u16;
typedef unsigned int   u32;
typedef __attribute__((ext_vector_type(8))) short short8;   // 8 bf16 = 4 VGPRs
typedef __attribute__((ext_vector_type(4))) float f32x4;

// ---------------- bf16 helpers (bit-level) ----------------------------------
__device__ __forceinline__ float bf2f(u16 b) {
  union { u32 u; float f; } v; v.u = ((u32)b) << 16; return v.f;
}
__device__ __forceinline__ u16 f2bf(float f) {
  union { float f; u32 u; } v; v.f = f;
  u32 u = v.u;
  return (u16)((u + 0x7fffu + ((u >> 16) & 1u)) >> 16);  // RNE
}
__device__ __forceinline__ u32 pk2(u16 a, u16 b) { return (u32)a | ((u32)b << 16); }

// ---------------- dtype probe: bf16 vs f32 ----------------------------------
__global__ void detect_dtype(const u16* __restrict__ xin, int* __restrict__ flag) {
  int hits = 0;
  for (int i = threadIdx.x; i < 16384; i += 256) {
    u16 v = xin[i];
    if (((v >> 7) & 0xFF) == 0xFF) hits++;
  }
  if (hits) atomicOr(flag, 1);
}

// ---------------- canonicalize a tensor to bf16 -----------------------------
__global__ __launch_bounds__(256) void convert_bf16(const void* __restrict__ src,
    u16* __restrict__ dst, int n, const int* __restrict__ flag) {
  int i = blockIdx.x * 256 + threadIdx.x;
  if (i >= n) return;
  if (*flag) dst[i] = f2bf(((const float*)src)[i]);
  else       dst[i] = ((const u16*)src)[i];
}

// ---------------- init: x_ws = f32(x_in[:, :64]), input row stride 65 -------
__global__ __launch_bounds__(256) void init_x(const void* __restrict__ xin,
    float* __restrict__ x, const int* __restrict__ flag, int N) {
  int idx = blockIdx.x * 256 + threadIdx.x;
  if (idx >= N * 64) return;
  int n = idx >> 6, c = idx & 63;
  size_t si = (size_t)n * 65 + c;
  float v = (*flag) ? ((const float*)xin)[si] : bf2f(((const u16*)xin)[si]);
  if (!isfinite(v)) v = 0.0f;
  x[idx] = v;
}

// ---------------- per-column sum & sumsq over N rows (initial stats) --------
__global__ __launch_bounds__(256) void col_stats(const float* __restrict__ x,
                                                 float* __restrict__ stats, int N) {
  int c   = threadIdx.x & 63;
  int sub = threadIdx.x >> 6;
  int rows = N / gridDim.x;
  int r0 = blockIdx.x * rows;
  float s = 0.f, s2 = 0.f;
  for (int r = sub; r < rows; r += 4) {
    float v = x[(size_t)(r0 + r) * 64 + c];
    s += v; s2 = fmaf(v, v, s2);
  }
  __shared__ float ls[256], lq[256];
  ls[threadIdx.x] = s; lq[threadIdx.x] = s2;
  __syncthreads();
  if (threadIdx.x < 64) {
    s  = ls[c] + ls[c + 64] + ls[c + 128] + ls[c + 192];
    s2 = lq[c] + lq[c + 64] + lq[c + 128] + lq[c + 192];
    atomicAdd(&stats[c], s);
    atomicAdd(&stats[64 + c], s2);
  }
}

// ============================================================================
// Fused coupling layer, round 7 = round-5 structure (best known: 188 us/layer)
// + manual register software-pipeline on GEMM0/GEMM1 (prefetch next
// iteration's W-frags + h0-frags while current MFMAs issue; wrap-around
// indices keep it branch-free so the compiler emits partial vmcnt waits).
// Block = 64 batch rows, 4 waves. Wave w owns h0/h1 column strip
// [w*128, (w+1)*128). GEMM1->GEMM2 round-trip through wave-PRIVATE LDS.
// Barriers per block: 6.
// MFMA mapping (validated r3-r5): frags X[r=lane&15][k=(lane>>4)*8+j],
// mfma(A,B) -> D[Arow=q*4+i][Brow=m].
// ============================================================================
__global__ __launch_bounds__(256, 2) void fused_layer(
    float* __restrict__ x, float* __restrict__ det,
    const float* __restrict__ statsC, float* __restrict__ statsN,
    const u16* __restrict__ W0s, const u16* __restrict__ B0s,
    const u16* __restrict__ W1s, const u16* __restrict__ B1s,
    const u16* __restrict__ W2s, const u16* __restrict__ B2s,
    const u16* __restrict__ W0t, const u16* __restrict__ B0t,
    const u16* __restrict__ W1t, const u16* __restrict__ B1t,
    const u16* __restrict__ W2t, const u16* __restrict__ B2t,
    int off1, int first, int N)
{
  __shared__ __align__(16) u16 h0s[64 * 512];   // 65536 B (XOR-swizzled groups)
  __shared__ __align__(16) u16 xh[6144];        // 12288 B (x1s, then h1w regions)
  __shared__ float musr[128];                   //   512 B
  __shared__ float csum[64], csqs[64];          //   512 B  => 78848 B total

  const int tid  = threadIdx.x;
  const int lane = tid & 63, wave = tid >> 6;
  const int m = lane & 15, q = lane >> 4;
  const int mb = m & 7;
  const int r0 = blockIdx.x * 64;
  const int off2 = 32 - off1;
  const float invN = 1.0f / (float)N;

  if (tid < 64) {
    float mu  = statsC[tid] * invN;
    float var = fmaxf(statsC[64 + tid] * invN - mu * mu, 0.0f);
    musr[tid]      = mu;
    musr[64 + tid] = 1.0f / sqrtf(var + 1e-5f);
    csum[tid] = 0.0f; csqs[tid] = 0.0f;
  }
  __syncthreads();

  // ---- stage normalized x1 (bf16) into xh (x1s layout) ----
  {
    int row = tid >> 2, kq = (tid & 3) * 8;
    const float* src = x + (size_t)(r0 + row) * 64 + off1 + kq;
    float4 v0 = *(const float4*)src;
    float4 v1 = *(const float4*)(src + 4);
    float vv[8] = {v0.x, v0.y, v0.z, v0.w, v1.x, v1.y, v1.z, v1.w};
    u16 pk[8];
    #pragma unroll
    for (int u_ = 0; u_ < 8; ++u_) {
      int c = off1 + kq + u_;
      pk[u_] = f2bf((vv[u_] - musr[c]) * musr[64 + c]);
    }
    *(uint4*)&xh[row * 40 + kq] =
        make_uint4(pk2(pk[0], pk[1]), pk2(pk[2], pk[3]),
                   pk2(pk[4], pk[5]), pk2(pk[6], pk[7]));
  }
  __syncthreads();

  // every wave loads all 4 row-block fragments of x1 (consumed before any
  // h1w write: first h1w write is after the GEMM0 barrier below)
  short8 xb[4];
  #pragma unroll
  for (int fm = 0; fm < 4; ++fm)
    xb[fm] = *(const short8*)&xh[(fm * 16 + m) * 40 + q * 8];

  const u16* W0p[2] = {W0s, W0t}; const u16* B0p[2] = {B0s, B0t};
  const u16* W1p[2] = {W1s, W1t}; const u16* B1p[2] = {B1s, B1t};
  const u16* W2p[2] = {W2s, W2t};

  const f32x4 fz = {0.f, 0.f, 0.f, 0.f};
  f32x4 a2[2][4][2];    // [path][fr][fo2] GEMM2 K-strip partials
  #pragma unroll
  for (int p = 0; p < 2; ++p)
    #pragma unroll
    for (int fr = 0; fr < 4; ++fr)
      #pragma unroll
      for (int fo2 = 0; fo2 < 2; ++fo2) a2[p][fr][fo2] = fz;

  short8 zf;
  #pragma unroll
  for (int j = 0; j < 8; ++j) zf[j] = 0;

  u16* h1w = &xh[wave * 1536];    // wave-private, row stride 24 u16 (48 B)

  #pragma unroll
  for (int p = 0; p < 2; ++p) {
    if (p == 1) __syncthreads();    // all s-path h0s reads done before overwrite
    const u16 *W0 = W0p[p], *B0 = B0p[p], *W1 = W1p[p], *B1 = B1p[p], *W2 = W2p[p];

    // ---- GEMM0: wave computes h0 col strip [wave*128, +128) over 64 rows ----
    // register-pipelined: W0 frag for fo+1 prefetched (wrap-around index).
    short8 w0n = *(const short8*)(W0 + (size_t)(wave * 128 + m) * 32 + q * 8);
    #pragma unroll
    for (int fo = 0; fo < 8; ++fo) {
      short8 w0c = w0n;
      int fn = (fo + 1) & 7;
      w0n = *(const short8*)(W0 + (size_t)(wave * 128 + fn * 16 + m) * 32 + q * 8);
      int colf = wave * 128 + fo * 16;
      int cb = colf + q * 4;
      float bb[4];
      #pragma unroll
      for (int i2 = 0; i2 < 4; ++i2) bb[i2] = bf2f(B0[cb + i2]);
      int gw = cb >> 3, wo = cb & 7;
      #pragma unroll
      for (int fm = 0; fm < 4; ++fm) {
        f32x4 d = __builtin_amdgcn_mfma_f32_16x16x32_bf16(w0c, xb[fm], fz, 0, 0, 0);
        u16 pk[4];
        #pragma unroll
        for (int i2 = 0; i2 < 4; ++i2) pk[i2] = f2bf(fmaxf(d[i2] + bb[i2], 0.0f));
        int row = fm * 16 + m;
        *(uint2*)&h0s[row * 512 + ((gw ^ (row & 7)) << 3) + wo] =
            make_uint2(pk2(pk[0], pk[1]), pk2(pk[2], pk[3]));
      }
    }
    __syncthreads();    // h0s strip writes visible to all waves

    // ---- GEMM1 + GEMM2 (no barriers; h1 round-trip is wave-private) ----
    #pragma unroll 1
    for (int oc2 = 0; oc2 < 2; ++oc2) {
      int ocb = wave * 128 + oc2 * 64;
      f32x4 c1[4][4];   // [fo][fm]
      #pragma unroll
      for (int fo = 0; fo < 4; ++fo)
        #pragma unroll
        for (int fm = 0; fm < 4; ++fm) c1[fo][fm] = fz;

      // software pipeline: prefetch ks+1's fragments while ks's MFMAs issue
      short8 wan[4], bfn[4];
      #pragma unroll
      for (int fm = 0; fm < 4; ++fm)
        bfn[fm] = *(const short8*)&h0s[(fm * 16 + m) * 512 + ((q ^ mb) << 3)];
      #pragma unroll
      for (int fo = 0; fo < 4; ++fo)
        wan[fo] = *(const short8*)(W1 + (size_t)(ocb + fo * 16 + m) * 512 + q * 8);

      #pragma unroll 4
      for (int ks = 0; ks < 16; ++ks) {
        short8 wac[4], bfc[4];
        #pragma unroll
        for (int z = 0; z < 4; ++z) { wac[z] = wan[z]; bfc[z] = bfn[z]; }
        int kn = (ks + 1) & 15;     // wrap: branch-free, always-valid prefetch
        #pragma unroll
        for (int fm = 0; fm < 4; ++fm)
          bfn[fm] = *(const short8*)&h0s[(fm * 16 + m) * 512 +
                                         ((((kn << 2) | q) ^ mb) << 3)];
        #pragma unroll
        for (int fo = 0; fo < 4; ++fo)
          wan[fo] = *(const short8*)(W1 + (size_t)(ocb + fo * 16 + m) * 512 +
                                     (kn << 5) + q * 8);
        #pragma unroll
        for (int fo = 0; fo < 4; ++fo)
          #pragma unroll
          for (int fm = 0; fm < 4; ++fm)
            c1[fo][fm] = __builtin_amdgcn_mfma_f32_16x16x32_bf16(
                wac[fo], bfc[fm], c1[fo][fm], 0, 0, 0);
      }

      // per-fo: h1 epilogue -> wave-private LDS -> GEMM2 K=16 chunk (padded)
      #pragma unroll
      for (int fo = 0; fo < 4; ++fo) {
        int colb = ocb + fo * 16 + q * 4;
        float bb[4];
        #pragma unroll
        for (int i2 = 0; i2 < 4; ++i2) bb[i2] = bf2f(B1[colb + i2]);
        #pragma unroll
        for (int fm = 0; fm < 4; ++fm) {
          u16 pk[4];
          #pragma unroll
          for (int i2 = 0; i2 < 4; ++i2)
            pk[i2] = f2bf(fmaxf(c1[fo][fm][i2] + bb[i2], 0.0f));
          *(uint2*)&h1w[(fm * 16 + m) * 24 + q * 4] =
              make_uint2(pk2(pk[0], pk[1]), pk2(pk[2], pk[3]));
        }
        asm volatile("s_waitcnt lgkmcnt(0)" ::: "memory");  // same-wave RAW
        int kb = ocb + fo * 16;
        #pragma unroll
        for (int fr = 0; fr < 4; ++fr) {
          short8 af = zf;                 // k>=16 lanes contribute zero
          if (q < 2) af = *(const short8*)&h1w[(fr * 16 + m) * 24 + q * 8];
          #pragma unroll
          for (int fo2 = 0; fo2 < 2; ++fo2) {
            short8 wf = *(const short8*)(W2 + (size_t)(fo2 * 16 + m) * 512 +
                                         kb + q * 8);
            a2[p][fr][fo2] = __builtin_amdgcn_mfma_f32_16x16x32_bf16(
                af, wf, a2[p][fr][fo2], 0, 0, 0);
          }
        }
      }
    }
  }
  __syncthreads();    // all GEMM2 done -> h0s region reusable as f32 scratch

  // ---- cross-wave reduction of GEMM2 partials (in h0s as f32) ----
  float* red = (float*)h0s;   // red[(path*4+wave)*64 + row]*32 + col
  #pragma unroll
  for (int fr = 0; fr < 4; ++fr)
    #pragma unroll
    for (int fo2 = 0; fo2 < 2; ++fo2)
      #pragma unroll
      for (int i2 = 0; i2 < 4; ++i2) {
        int row = fr * 16 + q * 4 + i2, col = fo2 * 16 + m;
        red[(wave * 64 + row) * 32 + col]       = a2[0][fr][fo2][i2];
        red[((4 + wave) * 64 + row) * 32 + col] = a2[1][fr][fo2][i2];
      }
  __syncthreads();

  // ---- coupling + det + next-layer stats ----
  {
    int col = tid & 31, rh = tid >> 5;    // col fixed per thread; rows u*8+rh
    float muA = musr[off1 + col], rsA = musr[64 + off1 + col];
    float muB = musr[off2 + col], rsB = musr[64 + off2 + col];
    float b2s = bf2f(B2s[col]), b2t = bf2f(B2t[col]);
    float cs1 = 0.f, cq1 = 0.f, cs2 = 0.f, cq2 = 0.f;
    #pragma unroll
    for (int u_ = 0; u_ < 8; ++u_) {
      int row = u_ * 8 + rh;
      float sv = b2s, tv = b2t;
      #pragma unroll
      for (int w = 0; w < 4; ++w) {
        sv += red[(w * 64 + row) * 32 + col];
        tv += red[((4 + w) * 64 + row) * 32 + col];
      }
      size_t rb = (size_t)(r0 + row) * 64;
      float x1n = (x[rb + off1 + col] - muA) * rsA;
      float x2n = (x[rb + off2 + col] - muB) * rsB;
      float y2 = fmaf(x2n, expf(fminf(sv, 30.0f)), tv);
      x[rb + col]      = x1n;
      x[rb + 32 + col] = y2;
      cs1 += x1n; cq1 = fmaf(x1n, x1n, cq1);
      cs2 += y2;  cq2 = fmaf(y2, y2, cq2);
      // det: row-sum of s over the 32 lanes sharing this row
      float rs_ = sv;
      rs_ += __shfl_xor(rs_, 1);  rs_ += __shfl_xor(rs_, 2);
      rs_ += __shfl_xor(rs_, 4);  rs_ += __shfl_xor(rs_, 8);
      rs_ += __shfl_xor(rs_, 16);
      if (col == 0) {
        int r = r0 + row;
        if (first) det[r] = rs_; else det[r] += rs_;
      }
    }
    // stats: fold lane L with L+32 (same col), then one atomic per wave/col
    cs1 += __shfl_xor(cs1, 32); cq1 += __shfl_xor(cq1, 32);
    cs2 += __shfl_xor(cs2, 32); cq2 += __shfl_xor(cq2, 32);
    if (lane < 32) {
      atomicAdd(&csum[col], cs1);      atomicAdd(&csqs[col], cq1);
      atomicAdd(&csum[32 + col], cs2); atomicAdd(&csqs[32 + col], cq2);
    }
  }
  __syncthreads();
  if (tid < 64) {
    atomicAdd(&statsN[tid],      csum[tid]);
    atomicAdd(&statsN[64 + tid], csqs[tid]);
  }
}

// ---------------- GMM log-likelihood + output writes + partial sums ---------
__global__ __launch_bounds__(256) void gmm_out(const float* __restrict__ x,
    const float* __restrict__ det, const u16* __restrict__ means,
    void* __restrict__ outv, double* __restrict__ acc,
    const int* __restrict__ flag, int N) {
  __shared__ float ms[640];
  __shared__ double rll[256], rdt[256];
  for (int i = threadIdx.x; i < 640; i += 256) ms[i] = bf2f(means[i]);
  __syncthreads();
  int of32 = *flag;
  int n = blockIdx.x * 256 + threadIdx.x;
  double llv = 0.0, dtv = 0.0;
  if (n < N) {
    float y[64];
    size_t rb = (size_t)n * 64;
    #pragma unroll
    for (int c = 0; c < 64; ++c) y[c] = x[rb + c];
    if (of32) {
      float* out = (float*)outv;
      #pragma unroll
      for (int c = 0; c < 64; ++c) out[rb + c] = y[c];
    } else {
      u16* out = (u16*)outv;
      #pragma unroll
      for (int c = 0; c < 64; ++c) out[rb + c] = f2bf(y[c]);
    }
    float lp[10];
    float mx = -3.0e38f;
    #pragma unroll
    for (int k = 0; k < 10; ++k) {
      float d2 = 0.0f;
      #pragma unroll
      for (int c = 0; c < 64; ++c) { float d = y[c] - ms[k * 64 + c]; d2 = fmaf(d, d, d2); }
      float v = -0.5f * (d2 + 64.0f * 1.8378770664093455f) - 2.302585092994046f;
      lp[k] = v; mx = fmaxf(mx, v);
    }
    float se = 0.0f;
    #pragma unroll
    for (int k = 0; k < 10; ++k) se += expf(lp[k] - mx);
    float ll = mx + logf(se);
    float dv = det[n];
    size_t NY = (size_t)N * 64;
    if (of32) {
      float* out = (float*)outv;
      out[NY + 1 + n]     = ll;
      out[NY + 1 + N + n] = dv;
    } else {
      u16* out = (u16*)outv;
      out[NY + 1 + n]     = f2bf(ll);
      out[NY + 1 + N + n] = f2bf(dv);
    }
    llv = ll; dtv = dv;
  }
  rll[threadIdx.x] = llv; rdt[threadIdx.x] = dtv;
  __syncthreads();
  for (int st = 128; st > 0; st >>= 1) {
    if (threadIdx.x < st) {
      rll[threadIdx.x] += rll[threadIdx.x + st];
      rdt[threadIdx.x] += rdt[threadIdx.x + st];
    }
    __syncthreads();
  }
  if (threadIdx.x == 0) { atomicAdd(&acc[0], rll[0]); atomicAdd(&acc[1], rdt[0]); }
}

// ---------------- scalars: loss, ll.mean, det.mean --------------------------
__global__ void finalize(const double* __restrict__ acc, void* __restrict__ outv,
                         const int* __restrict__ flag, int N) {
  double llm = acc[0] / (double)N;
  double dm  = acc[1] / (double)N;
  size_t NY = (size_t)N * 64;
  if (*flag) {
    float* out = (float*)outv;
    out[NY]                         = (float)(-(llm + dm));
    out[NY + 1 + 2 * (size_t)N]     = (float)llm;
    out[NY + 1 + 2 * (size_t)N + 1] = (float)dm;
  } else {
    u16* out = (u16*)outv;
    out[NY]                         = f2bf((float)(-(llm + dm)));
    out[NY + 1 + 2 * (size_t)N]     = f2bf((float)llm);
    out[NY + 1 + 2 * (size_t)N + 1] = f2bf((float)dm);
  }
}

// ============================================================================
extern "C" void kernel_launch(void* const* d_in, const int* in_sizes, int n_in,
                              void* d_out, int out_size, void* d_ws, size_t ws_size,
                              hipStream_t stream) {
  const int N = in_sizes[0] / 65;              // 65536
  (void)n_in; (void)out_size; (void)ws_size;

  char* ws = (char*)d_ws;
  size_t off = 0;
  auto alloc = [&](size_t bytes) -> void* {
    void* p = ws + off; off = (off + bytes + 255) & ~(size_t)255; return p;
  };
  int*    flag  = (int*)   alloc(4);
  double* acc   = (double*)alloc(2 * 8);
  float*  stats = (float*) alloc(9 * 128 * 4);   // slot l = stats of x before layer l
  float*  det   = (float*) alloc((size_t)N * 4);
  float*  x     = (float*) alloc((size_t)N * 64 * 4);

  static const int wcnt[13] = {
    8*512*32, 8*512, 8*512*512, 8*512, 8*32*512, 8*32,   // s-path
    8*512*32, 8*512, 8*512*512, 8*512, 8*32*512, 8*32,   // t-path
    10*64                                                // means
  };
  u16* wptr[13];
  for (int t = 0; t < 13; ++t) wptr[t] = (u16*)alloc((size_t)wcnt[t] * 2);

  // ---- dtype probe + canonicalize ----
  hipMemsetAsync(flag, 0, 4, stream);
  hipMemsetAsync(stats, 0, 9 * 128 * sizeof(float), stream);
  hipMemsetAsync(acc, 0, 2 * sizeof(double), stream);
  detect_dtype<<<dim3(1), dim3(256), 0, stream>>>((const u16*)d_in[0], flag);
  for (int t = 0; t < 13; ++t) {
    int n = wcnt[t];
    convert_bf16<<<dim3((n + 255) / 256), dim3(256), 0, stream>>>(
        d_in[t + 1], wptr[t], n, flag);
  }

  const int NE = N * 64;
  init_x<<<dim3((NE + 255) / 256), dim3(256), 0, stream>>>(d_in[0], x, flag, N);
  col_stats<<<dim3(256), dim3(256), 0, stream>>>(x, stats, N);   // slot 0

  for (int i = 0; i < 8; ++i) {
    fused_layer<<<dim3(N / 64), dim3(256), 0, stream>>>(
        x, det, stats + (size_t)i * 128, stats + (size_t)(i + 1) * 128,
        wptr[0]  + (size_t)i * 512 * 32,  wptr[1]  + (size_t)i * 512,
        wptr[2]  + (size_t)i * 512 * 512, wptr[3]  + (size_t)i * 512,
        wptr[4]  + (size_t)i * 32 * 512,  wptr[5]  + (size_t)i * 32,
        wptr[6]  + (size_t)i * 512 * 32,  wptr[7]  + (size_t)i * 512,
        wptr[8]  + (size_t)i * 512 * 512, wptr[9]  + (size_t)i * 512,
        wptr[10] + (size_t)i * 32 * 512,  wptr[11] + (size_t)i * 32,
        (i & 1) ? 32 : 0, (i == 0) ? 1 : 0, N);
  }

  gmm_out<<<dim3((N + 255) / 256), dim3(256), 0, stream>>>(x, det, wptr[12],
                                                           d_out, acc, flag, N);
  finalize<<<dim3(1), dim3(1), 0, stream>>>(acc, d_out, flag, N);
}

// Round 8
// 1136.393 us; speedup vs baseline: 3.4861x; 1.3656x over previous
//
#include <hip/hip_runtime.h>
#include <cstdint>
#include <cstddef>

typedef unsigned short u16;
typedef unsigned int   u32;
typedef __attribute__((ext_vector_type(8))) short short8;   // 8 bf16 = 4 VGPRs
typedef __attribute__((ext_vector_type(4))) float f32x4;

// ---------------- bf16 helpers (bit-level) ----------------------------------
__device__ __forceinline__ float bf2f(u16 b) {
  union { u32 u; float f; } v; v.u = ((u32)b) << 16; return v.f;
}
__device__ __forceinline__ u16 f2bf(float f) {
  union { float f; u32 u; } v; v.f = f;
  u32 u = v.u;
  return (u16)((u + 0x7fffu + ((u >> 16) & 1u)) >> 16);  // RNE
}
__device__ __forceinline__ u32 pk2(u16 a, u16 b) { return (u32)a | ((u32)b << 16); }

// ---------------- dtype probe: bf16 vs f32 ----------------------------------
__global__ void detect_dtype(const u16* __restrict__ xin, int* __restrict__ flag) {
  int hits = 0;
  for (int i = threadIdx.x; i < 16384; i += 256) {
    u16 v = xin[i];
    if (((v >> 7) & 0xFF) == 0xFF) hits++;
  }
  if (hits) atomicOr(flag, 1);
}

// ---------------- canonicalize a tensor to bf16 (biases / means) ------------
__global__ __launch_bounds__(256) void convert_bf16(const void* __restrict__ src,
    u16* __restrict__ dst, int n, const int* __restrict__ flag) {
  int i = blockIdx.x * 256 + threadIdx.x;
  if (i >= n) return;
  if (*flag) dst[i] = f2bf(((const float*)src)[i]);
  else       dst[i] = ((const u16*)src)[i];
}

// ============================================================================
// Weight repack kernels: canonical [O][K] -> MFMA-fragment-major. Each frag is
// 64 lanes x 8 bf16 = 1 KB contiguous; lane (m=lane&15,q=lane>>4) holds
// element (row_base+m, col_base+q*8+j). One thread per lane (8 elems).
// This turns the fused kernel's strided 16-transaction frag loads into a
// single coalesced 1 KB read.
// ============================================================================
__global__ __launch_bounds__(256) void repack_w0(const void* __restrict__ src,
    u16* __restrict__ dst, const int* __restrict__ flag, int L) {
  int idx = blockIdx.x * 256 + threadIdx.x;
  if (idx >= L * 2048) return;
  int layer = idx >> 11, r = idx & 2047;
  int lane = r & 63, fo = (r >> 6) & 7, w = r >> 9;
  int m = lane & 15, q = lane >> 4;
  int row = w * 128 + fo * 16 + m;
  size_t s = (size_t)layer * 16384 + (size_t)row * 32 + q * 8;
  u16 o[8];
  if (*flag) { const float* p = (const float*)src;
    #pragma unroll
    for (int j = 0; j < 8; ++j) o[j] = f2bf(p[s + j]);
  } else { const u16* p = (const u16*)src;
    #pragma unroll
    for (int j = 0; j < 8; ++j) o[j] = p[s + j];
  }
  *(uint4*)&dst[(size_t)idx * 8] =
      make_uint4(pk2(o[0], o[1]), pk2(o[2], o[3]), pk2(o[4], o[5]), pk2(o[6], o[7]));
}

__global__ __launch_bounds__(256) void repack_w1(const void* __restrict__ src,
    u16* __restrict__ dst, const int* __restrict__ flag, int L) {
  int idx = blockIdx.x * 256 + threadIdx.x;
  if (idx >= L * 32768) return;
  int layer = idx >> 15, r = idx & 32767;
  int lane = r & 63, fo = (r >> 6) & 3, ks = (r >> 8) & 15;
  int oc2 = (r >> 12) & 1, w = (r >> 13) & 3;
  int m = lane & 15, q = lane >> 4;
  int row = w * 128 + oc2 * 64 + fo * 16 + m;
  int col = ks * 32 + q * 8;
  size_t s = (size_t)layer * 262144 + (size_t)row * 512 + col;
  u16 o[8];
  if (*flag) { const float* p = (const float*)src;
    #pragma unroll
    for (int j = 0; j < 8; ++j) o[j] = f2bf(p[s + j]);
  } else { const u16* p = (const u16*)src;
    #pragma unroll
    for (int j = 0; j < 8; ++j) o[j] = p[s + j];
  }
  *(uint4*)&dst[(size_t)idx * 8] =
      make_uint4(pk2(o[0], o[1]), pk2(o[2], o[3]), pk2(o[4], o[5]), pk2(o[6], o[7]));
}

__global__ __launch_bounds__(256) void repack_w2(const void* __restrict__ src,
    u16* __restrict__ dst, const int* __restrict__ flag, int L) {
  int idx = blockIdx.x * 256 + threadIdx.x;
  if (idx >= L * 4096) return;
  int layer = idx >> 12, r = idx & 4095;
  int lane = r & 63, fo2 = (r >> 6) & 1, fo = (r >> 7) & 3;
  int oc2 = (r >> 9) & 1, w = (r >> 10) & 3;
  int m = lane & 15, q = lane >> 4;
  int row = fo2 * 16 + m;
  int col = w * 128 + oc2 * 64 + fo * 16 + q * 8;   // may exceed 511 (padded k)
  u16 o[8];
  #pragma unroll
  for (int j = 0; j < 8; ++j) {
    int cj = col + j;
    if (cj < 512) {
      size_t s = (size_t)layer * 16384 + (size_t)row * 512 + cj;
      o[j] = (*flag) ? f2bf(((const float*)src)[s]) : ((const u16*)src)[s];
    } else o[j] = 0;
  }
  *(uint4*)&dst[(size_t)idx * 8] =
      make_uint4(pk2(o[0], o[1]), pk2(o[2], o[3]), pk2(o[4], o[5]), pk2(o[6], o[7]));
}

// ---------------- init: x_ws = f32(x_in[:, :64]), input row stride 65 -------
__global__ __launch_bounds__(256) void init_x(const void* __restrict__ xin,
    float* __restrict__ x, const int* __restrict__ flag, int N) {
  int idx = blockIdx.x * 256 + threadIdx.x;
  if (idx >= N * 64) return;
  int n = idx >> 6, c = idx & 63;
  size_t si = (size_t)n * 65 + c;
  float v = (*flag) ? ((const float*)xin)[si] : bf2f(((const u16*)xin)[si]);
  if (!isfinite(v)) v = 0.0f;
  x[idx] = v;
}

// ---------------- per-column sum & sumsq over N rows (initial stats) --------
__global__ __launch_bounds__(256) void col_stats(const float* __restrict__ x,
                                                 float* __restrict__ stats, int N) {
  int c   = threadIdx.x & 63;
  int sub = threadIdx.x >> 6;
  int rows = N / gridDim.x;
  int r0 = blockIdx.x * rows;
  float s = 0.f, s2 = 0.f;
  for (int r = sub; r < rows; r += 4) {
    float v = x[(size_t)(r0 + r) * 64 + c];
    s += v; s2 = fmaf(v, v, s2);
  }
  __shared__ float ls[256], lq[256];
  ls[threadIdx.x] = s; lq[threadIdx.x] = s2;
  __syncthreads();
  if (threadIdx.x < 64) {
    s  = ls[c] + ls[c + 64] + ls[c + 128] + ls[c + 192];
    s2 = lq[c] + lq[c + 64] + lq[c + 128] + lq[c + 192];
    atomicAdd(&stats[c], s);
    atomicAdd(&stats[64 + c], s2);
  }
}

// ============================================================================
// Fused coupling layer, round 8 = round-5/7 structure with all weight loads
// reading the fragment-major packed buffers (coalesced 1 KB per frag).
// Block = 64 batch rows, 4 waves; wave w owns h0/h1 col strip [w*128,+128).
// MFMA mapping (validated r3-r7): frags X[r=lane&15][k=(lane>>4)*8+j],
// mfma(A,B) -> D[Arow=q*4+i][Brow=m].
// ============================================================================
__global__ __launch_bounds__(256, 2) void fused_layer(
    float* __restrict__ x, float* __restrict__ det,
    const float* __restrict__ statsC, float* __restrict__ statsN,
    const u16* __restrict__ pW0s, const u16* __restrict__ B0s,
    const u16* __restrict__ pW1s, const u16* __restrict__ B1s,
    const u16* __restrict__ pW2s, const u16* __restrict__ B2s,
    const u16* __restrict__ pW0t, const u16* __restrict__ B0t,
    const u16* __restrict__ pW1t, const u16* __restrict__ B1t,
    const u16* __restrict__ pW2t, const u16* __restrict__ B2t,
    int off1, int first, int N)
{
  __shared__ __align__(16) u16 h0s[64 * 512];   // 65536 B (XOR-swizzled groups)
  __shared__ __align__(16) u16 xh[6144];        // 12288 B (x1s, then h1w regions)
  __shared__ float musr[128];                   //   512 B
  __shared__ float csum[64], csqs[64];          //   512 B  => 78848 B total

  const int tid  = threadIdx.x;
  const int lane = tid & 63, wave = tid >> 6;
  const int m = lane & 15, q = lane >> 4;
  const int mb = m & 7;
  const int r0 = blockIdx.x * 64;
  const int off2 = 32 - off1;
  const float invN = 1.0f / (float)N;

  if (tid < 64) {
    float mu  = statsC[tid] * invN;
    float var = fmaxf(statsC[64 + tid] * invN - mu * mu, 0.0f);
    musr[tid]      = mu;
    musr[64 + tid] = 1.0f / sqrtf(var + 1e-5f);
    csum[tid] = 0.0f; csqs[tid] = 0.0f;
  }
  __syncthreads();

  // ---- stage normalized x1 (bf16) into xh (x1s layout) ----
  {
    int row = tid >> 2, kq = (tid & 3) * 8;
    const float* src = x + (size_t)(r0 + row) * 64 + off1 + kq;
    float4 v0 = *(const float4*)src;
    float4 v1 = *(const float4*)(src + 4);
    float vv[8] = {v0.x, v0.y, v0.z, v0.w, v1.x, v1.y, v1.z, v1.w};
    u16 pk[8];
    #pragma unroll
    for (int u_ = 0; u_ < 8; ++u_) {
      int c = off1 + kq + u_;
      pk[u_] = f2bf((vv[u_] - musr[c]) * musr[64 + c]);
    }
    *(uint4*)&xh[row * 40 + kq] =
        make_uint4(pk2(pk[0], pk[1]), pk2(pk[2], pk[3]),
                   pk2(pk[4], pk[5]), pk2(pk[6], pk[7]));
  }
  __syncthreads();

  short8 xb[4];
  #pragma unroll
  for (int fm = 0; fm < 4; ++fm)
    xb[fm] = *(const short8*)&xh[(fm * 16 + m) * 40 + q * 8];

  const u16* W0p[2] = {pW0s, pW0t}; const u16* B0p[2] = {B0s, B0t};
  const u16* W1p[2] = {pW1s, pW1t}; const u16* B1p[2] = {B1s, B1t};
  const u16* W2p[2] = {pW2s, pW2t};

  const f32x4 fz = {0.f, 0.f, 0.f, 0.f};
  f32x4 a2[2][4][2];    // [path][fr][fo2] GEMM2 K-strip partials
  #pragma unroll
  for (int p = 0; p < 2; ++p)
    #pragma unroll
    for (int fr = 0; fr < 4; ++fr)
      #pragma unroll
      for (int fo2 = 0; fo2 < 2; ++fo2) a2[p][fr][fo2] = fz;

  short8 zf;
  #pragma unroll
  for (int j = 0; j < 8; ++j) zf[j] = 0;

  u16* h1w = &xh[wave * 1536];    // wave-private, row stride 24 u16 (48 B)

  #pragma unroll
  for (int p = 0; p < 2; ++p) {
    if (p == 1) __syncthreads();    // all s-path h0s reads done before overwrite
    const u16 *W0 = W0p[p], *B0 = B0p[p], *W1 = W1p[p], *B1 = B1p[p], *W2 = W2p[p];

    // ---- GEMM0: wave computes h0 col strip [wave*128, +128) over 64 rows ----
    // packed frag: W0 + (wave*8+fo)*512 + lane*8  (contiguous 1 KB)
    short8 w0n = *(const short8*)(W0 + (size_t)(wave * 8) * 512 + lane * 8);
    #pragma unroll
    for (int fo = 0; fo < 8; ++fo) {
      short8 w0c = w0n;
      int fn = (fo + 1) & 7;
      w0n = *(const short8*)(W0 + (size_t)(wave * 8 + fn) * 512 + lane * 8);
      int colf = wave * 128 + fo * 16;
      int cb = colf + q * 4;
      float bb[4];
      #pragma unroll
      for (int i2 = 0; i2 < 4; ++i2) bb[i2] = bf2f(B0[cb + i2]);
      int gw = cb >> 3, wo = cb & 7;
      #pragma unroll
      for (int fm = 0; fm < 4; ++fm) {
        f32x4 d = __builtin_amdgcn_mfma_f32_16x16x32_bf16(w0c, xb[fm], fz, 0, 0, 0);
        u16 pk[4];
        #pragma unroll
        for (int i2 = 0; i2 < 4; ++i2) pk[i2] = f2bf(fmaxf(d[i2] + bb[i2], 0.0f));
        int row = fm * 16 + m;
        *(uint2*)&h0s[row * 512 + ((gw ^ (row & 7)) << 3) + wo] =
            make_uint2(pk2(pk[0], pk[1]), pk2(pk[2], pk[3]));
      }
    }
    __syncthreads();    // h0s strip writes visible to all waves

    // ---- GEMM1 + GEMM2 (no barriers; h1 round-trip is wave-private) ----
    #pragma unroll 1
    for (int oc2 = 0; oc2 < 2; ++oc2) {
      int ocb = wave * 128 + oc2 * 64;
      const u16* W1b = W1 + (size_t)(wave * 2 + oc2) * 32768;  // strip base
      f32x4 c1[4][4];   // [fo][fm]
      #pragma unroll
      for (int fo = 0; fo < 4; ++fo)
        #pragma unroll
        for (int fm = 0; fm < 4; ++fm) c1[fo][fm] = fz;

      // software pipeline: prefetch ks+1's fragments while ks's MFMAs issue
      short8 wan[4], bfn[4];
      #pragma unroll
      for (int fm = 0; fm < 4; ++fm)
        bfn[fm] = *(const short8*)&h0s[(fm * 16 + m) * 512 + ((q ^ mb) << 3)];
      #pragma unroll
      for (int fo = 0; fo < 4; ++fo)
        wan[fo] = *(const short8*)(W1b + fo * 512 + lane * 8);

      #pragma unroll 4
      for (int ks = 0; ks < 16; ++ks) {
        short8 wac[4], bfc[4];
        #pragma unroll
        for (int z = 0; z < 4; ++z) { wac[z] = wan[z]; bfc[z] = bfn[z]; }
        int kn = (ks + 1) & 15;     // wrap: branch-free, always-valid prefetch
        #pragma unroll
        for (int fm = 0; fm < 4; ++fm)
          bfn[fm] = *(const short8*)&h0s[(fm * 16 + m) * 512 +
                                         ((((kn << 2) | q) ^ mb) << 3)];
        #pragma unroll
        for (int fo = 0; fo < 4; ++fo)
          wan[fo] = *(const short8*)(W1b + (size_t)kn * 2048 + fo * 512 + lane * 8);
        #pragma unroll
        for (int fo = 0; fo < 4; ++fo)
          #pragma unroll
          for (int fm = 0; fm < 4; ++fm)
            c1[fo][fm] = __builtin_amdgcn_mfma_f32_16x16x32_bf16(
                wac[fo], bfc[fm], c1[fo][fm], 0, 0, 0);
      }

      // per-fo: h1 epilogue -> wave-private LDS -> GEMM2 K=16 chunk (padded)
      #pragma unroll
      for (int fo = 0; fo < 4; ++fo) {
        int colb = ocb + fo * 16 + q * 4;
        float bb[4];
        #pragma unroll
        for (int i2 = 0; i2 < 4; ++i2) bb[i2] = bf2f(B1[colb + i2]);
        #pragma unroll
        for (int fm = 0; fm < 4; ++fm) {
          u16 pk[4];
          #pragma unroll
          for (int i2 = 0; i2 < 4; ++i2)
            pk[i2] = f2bf(fmaxf(c1[fo][fm][i2] + bb[i2], 0.0f));
          *(uint2*)&h1w[(fm * 16 + m) * 24 + q * 4] =
              make_uint2(pk2(pk[0], pk[1]), pk2(pk[2], pk[3]));
        }
        asm volatile("s_waitcnt lgkmcnt(0)" ::: "memory");  // same-wave RAW
        // packed W2 frag: ((wave*2+oc2)*8 + fo*2 + fo2)*512 + lane*8
        const u16* W2b = W2 + (size_t)((wave * 2 + oc2) * 8 + fo * 2) * 512;
        #pragma unroll
        for (int fr = 0; fr < 4; ++fr) {
          short8 af = zf;                 // k>=16 lanes contribute zero
          if (q < 2) af = *(const short8*)&h1w[(fr * 16 + m) * 24 + q * 8];
          #pragma unroll
          for (int fo2 = 0; fo2 < 2; ++fo2) {
            short8 wf = *(const short8*)(W2b + fo2 * 512 + lane * 8);
            a2[p][fr][fo2] = __builtin_amdgcn_mfma_f32_16x16x32_bf16(
                af, wf, a2[p][fr][fo2], 0, 0, 0);
          }
        }
      }
    }
  }
  __syncthreads();    // all GEMM2 done -> h0s region reusable as f32 scratch

  // ---- cross-wave reduction of GEMM2 partials (in h0s as f32) ----
  float* red = (float*)h0s;   // red[(path*4+wave)*64 + row]*32 + col
  #pragma unroll
  for (int fr = 0; fr < 4; ++fr)
    #pragma unroll
    for (int fo2 = 0; fo2 < 2; ++fo2)
      #pragma unroll
      for (int i2 = 0; i2 < 4; ++i2) {
        int row = fr * 16 + q * 4 + i2, col = fo2 * 16 + m;
        red[(wave * 64 + row) * 32 + col]       = a2[0][fr][fo2][i2];
        red[((4 + wave) * 64 + row) * 32 + col] = a2[1][fr][fo2][i2];
      }
  __syncthreads();

  // ---- coupling + det + next-layer stats ----
  {
    int col = tid & 31, rh = tid >> 5;    // col fixed per thread; rows u*8+rh
    float muA = musr[off1 + col], rsA = musr[64 + off1 + col];
    float muB = musr[off2 + col], rsB = musr[64 + off2 + col];
    float b2s = bf2f(B2s[col]), b2t = bf2f(B2t[col]);
    float cs1 = 0.f, cq1 = 0.f, cs2 = 0.f, cq2 = 0.f;
    #pragma unroll
    for (int u_ = 0; u_ < 8; ++u_) {
      int row = u_ * 8 + rh;
      float sv = b2s, tv = b2t;
      #pragma unroll
      for (int w = 0; w < 4; ++w) {
        sv += red[(w * 64 + row) * 32 + col];
        tv += red[((4 + w) * 64 + row) * 32 + col];
      }
      size_t rb = (size_t)(r0 + row) * 64;
      float x1n = (x[rb + off1 + col] - muA) * rsA;
      float x2n = (x[rb + off2 + col] - muB) * rsB;
      float y2 = fmaf(x2n, expf(fminf(sv, 30.0f)), tv);
      x[rb + col]      = x1n;
      x[rb + 32 + col] = y2;
      cs1 += x1n; cq1 = fmaf(x1n, x1n, cq1);
      cs2 += y2;  cq2 = fmaf(y2, y2, cq2);
      float rs_ = sv;
      rs_ += __shfl_xor(rs_, 1);  rs_ += __shfl_xor(rs_, 2);
      rs_ += __shfl_xor(rs_, 4);  rs_ += __shfl_xor(rs_, 8);
      rs_ += __shfl_xor(rs_, 16);
      if (col == 0) {
        int r = r0 + row;
        if (first) det[r] = rs_; else det[r] += rs_;
      }
    }
    cs1 += __shfl_xor(cs1, 32); cq1 += __shfl_xor(cq1, 32);
    cs2 += __shfl_xor(cs2, 32); cq2 += __shfl_xor(cq2, 32);
    if (lane < 32) {
      atomicAdd(&csum[col], cs1);      atomicAdd(&csqs[col], cq1);
      atomicAdd(&csum[32 + col], cs2); atomicAdd(&csqs[32 + col], cq2);
    }
  }
  __syncthreads();
  if (tid < 64) {
    atomicAdd(&statsN[tid],      csum[tid]);
    atomicAdd(&statsN[64 + tid], csqs[tid]);
  }
}

// ---------------- GMM log-likelihood + output writes + partial sums ---------
__global__ __launch_bounds__(256) void gmm_out(const float* __restrict__ x,
    const float* __restrict__ det, const u16* __restrict__ means,
    void* __restrict__ outv, double* __restrict__ acc,
    const int* __restrict__ flag, int N) {
  __shared__ float ms[640];
  __shared__ double rll[256], rdt[256];
  for (int i = threadIdx.x; i < 640; i += 256) ms[i] = bf2f(means[i]);
  __syncthreads();
  int of32 = *flag;
  int n = blockIdx.x * 256 + threadIdx.x;
  double llv = 0.0, dtv = 0.0;
  if (n < N) {
    float y[64];
    size_t rb = (size_t)n * 64;
    #pragma unroll
    for (int c = 0; c < 64; ++c) y[c] = x[rb + c];
    if (of32) {
      float* out = (float*)outv;
      #pragma unroll
      for (int c = 0; c < 64; ++c) out[rb + c] = y[c];
    } else {
      u16* out = (u16*)outv;
      #pragma unroll
      for (int c = 0; c < 64; ++c) out[rb + c] = f2bf(y[c]);
    }
    float lp[10];
    float mx = -3.0e38f;
    #pragma unroll
    for (int k = 0; k < 10; ++k) {
      float d2 = 0.0f;
      #pragma unroll
      for (int c = 0; c < 64; ++c) { float d = y[c] - ms[k * 64 + c]; d2 = fmaf(d, d, d2); }
      float v = -0.5f * (d2 + 64.0f * 1.8378770664093455f) - 2.302585092994046f;
      lp[k] = v; mx = fmaxf(mx, v);
    }
    float se = 0.0f;
    #pragma unroll
    for (int k = 0; k < 10; ++k) se += expf(lp[k] - mx);
    float ll = mx + logf(se);
    float dv = det[n];
    size_t NY = (size_t)N * 64;
    if (of32) {
      float* out = (float*)outv;
      out[NY + 1 + n]     = ll;
      out[NY + 1 + N + n] = dv;
    } else {
      u16* out = (u16*)outv;
      out[NY + 1 + n]     = f2bf(ll);
      out[NY + 1 + N + n] = f2bf(dv);
    }
    llv = ll; dtv = dv;
  }
  rll[threadIdx.x] = llv; rdt[threadIdx.x] = dtv;
  __syncthreads();
  for (int st = 128; st > 0; st >>= 1) {
    if (threadIdx.x < st) {
      rll[threadIdx.x] += rll[threadIdx.x + st];
      rdt[threadIdx.x] += rdt[threadIdx.x + st];
    }
    __syncthreads();
  }
  if (threadIdx.x == 0) { atomicAdd(&acc[0], rll[0]); atomicAdd(&acc[1], rdt[0]); }
}

// ---------------- scalars: loss, ll.mean, det.mean --------------------------
__global__ void finalize(const double* __restrict__ acc, void* __restrict__ outv,
                         const int* __restrict__ flag, int N) {
  double llm = acc[0] / (double)N;
  double dm  = acc[1] / (double)N;
  size_t NY = (size_t)N * 64;
  if (*flag) {
    float* out = (float*)outv;
    out[NY]                         = (float)(-(llm + dm));
    out[NY + 1 + 2 * (size_t)N]     = (float)llm;
    out[NY + 1 + 2 * (size_t)N + 1] = (float)dm;
  } else {
    u16* out = (u16*)outv;
    out[NY]                         = f2bf((float)(-(llm + dm)));
    out[NY + 1 + 2 * (size_t)N]     = f2bf((float)llm);
    out[NY + 1 + 2 * (size_t)N + 1] = f2bf((float)dm);
  }
}

// ============================================================================
extern "C" void kernel_launch(void* const* d_in, const int* in_sizes, int n_in,
                              void* d_out, int out_size, void* d_ws, size_t ws_size,
                              hipStream_t stream) {
  const int N = in_sizes[0] / 65;              // 65536
  (void)n_in; (void)out_size; (void)ws_size;

  char* ws = (char*)d_ws;
  size_t off = 0;
  auto alloc = [&](size_t bytes) -> void* {
    void* p = ws + off; off = (off + bytes + 255) & ~(size_t)255; return p;
  };
  int*    flag  = (int*)   alloc(4);
  double* acc   = (double*)alloc(2 * 8);
  float*  stats = (float*) alloc(9 * 128 * 4);   // slot l = stats of x before layer l
  float*  det   = (float*) alloc((size_t)N * 4);
  float*  x     = (float*) alloc((size_t)N * 64 * 4);

  // packed weights (fragment-major)
  u16* pW0s = (u16*)alloc((size_t)8 * 16384 * 2);
  u16* pW0t = (u16*)alloc((size_t)8 * 16384 * 2);
  u16* pW1s = (u16*)alloc((size_t)8 * 262144 * 2);
  u16* pW1t = (u16*)alloc((size_t)8 * 262144 * 2);
  u16* pW2s = (u16*)alloc((size_t)8 * 32768 * 2);
  u16* pW2t = (u16*)alloc((size_t)8 * 32768 * 2);

  // canonical bf16 biases + means
  static const int bcnt[7] = {8*512, 8*512, 8*32, 8*512, 8*512, 8*32, 640};
  static const int bsrc[7] = {2, 4, 6, 8, 10, 12, 13};
  u16* bptr[7];
  for (int t = 0; t < 7; ++t) bptr[t] = (u16*)alloc((size_t)bcnt[t] * 2);

  // ---- dtype probe + canonicalize + repack ----
  hipMemsetAsync(flag, 0, 4, stream);
  hipMemsetAsync(stats, 0, 9 * 128 * sizeof(float), stream);
  hipMemsetAsync(acc, 0, 2 * sizeof(double), stream);
  detect_dtype<<<dim3(1), dim3(256), 0, stream>>>((const u16*)d_in[0], flag);
  for (int t = 0; t < 7; ++t) {
    int n = bcnt[t];
    convert_bf16<<<dim3((n + 255) / 256), dim3(256), 0, stream>>>(
        d_in[bsrc[t]], bptr[t], n, flag);
  }
  repack_w0<<<dim3(64),   dim3(256), 0, stream>>>(d_in[1],  pW0s, flag, 8);
  repack_w0<<<dim3(64),   dim3(256), 0, stream>>>(d_in[7],  pW0t, flag, 8);
  repack_w1<<<dim3(1024), dim3(256), 0, stream>>>(d_in[3],  pW1s, flag, 8);
  repack_w1<<<dim3(1024), dim3(256), 0, stream>>>(d_in[9],  pW1t, flag, 8);
  repack_w2<<<dim3(128),  dim3(256), 0, stream>>>(d_in[5],  pW2s, flag, 8);
  repack_w2<<<dim3(128),  dim3(256), 0, stream>>>(d_in[11], pW2t, flag, 8);

  const int NE = N * 64;
  init_x<<<dim3((NE + 255) / 256), dim3(256), 0, stream>>>(d_in[0], x, flag, N);
  col_stats<<<dim3(256), dim3(256), 0, stream>>>(x, stats, N);   // slot 0

  for (int i = 0; i < 8; ++i) {
    fused_layer<<<dim3(N / 64), dim3(256), 0, stream>>>(
        x, det, stats + (size_t)i * 128, stats + (size_t)(i + 1) * 128,
        pW0s + (size_t)i * 16384,  bptr[0] + (size_t)i * 512,
        pW1s + (size_t)i * 262144, bptr[1] + (size_t)i * 512,
        pW2s + (size_t)i * 32768,  bptr[2] + (size_t)i * 32,
        pW0t + (size_t)i * 16384,  bptr[3] + (size_t)i * 512,
        pW1t + (size_t)i * 262144, bptr[4] + (size_t)i * 512,
        pW2t + (size_t)i * 32768,  bptr[5] + (size_t)i * 32,
        (i & 1) ? 32 : 0, (i == 0) ? 1 : 0, N);
  }

  gmm_out<<<dim3((N + 255) / 256), dim3(256), 0, stream>>>(x, det, bptr[6],
                                                           d_out, acc, flag, N);
  finalize<<<dim3(1), dim3(1), 0, stream>>>(acc, d_out, flag, N);
}